// Round 5
// baseline (513.306 us; speedup 1.0000x reference)
//
#include <hip/hip_runtime.h>
#include <hip/hip_bf16.h>

#define N_NODES 50000
#define N_EDGES 1000000
#define F_IN 256
#define C1 128      // HEADS*HID
#define HEADS 8
#define CLS 40
#define NEG_SLOPE 0.2f
#define EPS_GAT 1e-16f

// ---------------------------------------------------------------------------
// GEMM1: h1 = x @ W1  [N,256]x[256,128], fused attention dots.
// block = 256 threads, tile = 64 rows x 128 cols, K chunks of 32.
// thread micro-tile 8x4 (tx = col-group of 4, ty = row-group of 8).
// Per kk: 3x ds_read_b128 + 32 fma -> better VALU ratio than 4x4.
// ---------------------------------------------------------------------------
__global__ __launch_bounds__(256) void gemm1_kernel(
    const float* __restrict__ x, const float* __restrict__ W1,
    const float* __restrict__ att_s, const float* __restrict__ att_d,
    float* __restrict__ h1, float* __restrict__ a_s1, float* __restrict__ a_d1) {
  __shared__ float xs_t[32][72];   // [k][row64], pad 72 (288B, 16B-aligned)
  __shared__ float ws[32][128];    // [k][col]
  const int t = threadIdx.x;
  const int tx = t & 31, ty = t >> 5;   // ty in 0..7
  const int r0 = blockIdx.x * 64;
  float acc[8][4] = {};
  for (int k0 = 0; k0 < F_IN; k0 += 32) {
    __syncthreads();
    // W chunk: 32x128 = 4096 floats, 4 float4 per thread
    const float4* Wv = (const float4*)(W1 + k0 * C1);
#pragma unroll
    for (int i = 0; i < 4; ++i) {
      int f4 = t + i * 256;
      *(float4*)&ws[f4 >> 5][(f4 & 31) * 4] = Wv[f4];
    }
    // x chunk: 64 rows x 32 k = 512 float4, 2 per thread, stored transposed
#pragma unroll
    for (int i = 0; i < 2; ++i) {
      int f4 = t + i * 256;
      int rr = f4 >> 3;              // 8 float4 per row
      int k4 = (f4 & 7) * 4;
      int grow = min(r0 + rr, N_NODES - 1);
      float4 v = *(const float4*)&x[grow * F_IN + k0 + k4];
      xs_t[k4][rr] = v.x; xs_t[k4 + 1][rr] = v.y;
      xs_t[k4 + 2][rr] = v.z; xs_t[k4 + 3][rr] = v.w;
    }
    __syncthreads();
#pragma unroll
    for (int kk = 0; kk < 32; ++kk) {
      float4 a0v = *(float4*)&xs_t[kk][ty * 8];
      float4 a1v = *(float4*)&xs_t[kk][ty * 8 + 4];
      float4 bv  = *(float4*)&ws[kk][tx * 4];
      float a[8] = {a0v.x, a0v.y, a0v.z, a0v.w, a1v.x, a1v.y, a1v.z, a1v.w};
      float b[4] = {bv.x, bv.y, bv.z, bv.w};
#pragma unroll
      for (int i = 0; i < 8; ++i)
#pragma unroll
        for (int j = 0; j < 4; ++j) acc[i][j] = fmaf(a[i], b[j], acc[i][j]);
    }
  }
  // epilogue: store h1, fused a_s/a_d (head = 16 cols = 4 tx lanes)
  float as_c[4], ad_c[4];
#pragma unroll
  for (int j = 0; j < 4; ++j) { as_c[j] = att_s[tx * 4 + j]; ad_c[j] = att_d[tx * 4 + j]; }
  const int head = tx >> 2;
#pragma unroll
  for (int i = 0; i < 8; ++i) {
    int row = r0 + ty * 8 + i;
    float ps = acc[i][0] * as_c[0] + acc[i][1] * as_c[1] + acc[i][2] * as_c[2] + acc[i][3] * as_c[3];
    float pd = acc[i][0] * ad_c[0] + acc[i][1] * ad_c[1] + acc[i][2] * ad_c[2] + acc[i][3] * ad_c[3];
    ps += __shfl_xor(ps, 1); ps += __shfl_xor(ps, 2);
    pd += __shfl_xor(pd, 1); pd += __shfl_xor(pd, 2);
    if (row < N_NODES) {
      *(float4*)&h1[row * C1 + tx * 4] = make_float4(acc[i][0], acc[i][1], acc[i][2], acc[i][3]);
      if ((tx & 3) == 0) { a_s1[row * HEADS + head] = ps; a_d1[row * HEADS + head] = pd; }
    }
  }
}

// ---------------------------------------------------------------------------
// CSR build: zero, histogram over dst, single-block scan (also seeds cursor),
// scatter (atomic bump on cursor directly — no indptr re-load per edge).
// ---------------------------------------------------------------------------
__global__ void zero_kernel(int* __restrict__ deg) {
  int i = blockIdx.x * 256 + threadIdx.x;
  if (i < N_NODES) deg[i] = 0;
}

__global__ void hist_kernel(const int* __restrict__ ei, int* __restrict__ deg) {
  int e = blockIdx.x * 256 + threadIdx.x;
  if (e < N_EDGES) atomicAdd(&deg[ei[N_EDGES + e]], 1);
}

__global__ __launch_bounds__(1024) void scan_kernel(const int* __restrict__ deg,
                                                    int* __restrict__ indptr,
                                                    int* __restrict__ cursor) {
  __shared__ int part[1024];
  const int t = threadIdx.x;
  const int CH = (N_NODES + 1023) / 1024;  // 49
  int lo = t * CH, hi = min(lo + CH, N_NODES);
  if (lo > hi) lo = hi;
  int s = 0;
  for (int i = lo; i < hi; ++i) s += deg[i];
  part[t] = s;
  __syncthreads();
  for (int off = 1; off < 1024; off <<= 1) {
    int v = (t >= off) ? part[t - off] : 0;
    __syncthreads();
    part[t] += v;
    __syncthreads();
  }
  int run = (t > 0) ? part[t - 1] : 0;
  for (int i = lo; i < hi; ++i) { indptr[i] = run; cursor[i] = run; run += deg[i]; }
  if (t == 1023) indptr[N_NODES] = run;
}

__global__ void scatter_kernel(const int* __restrict__ ei,
                               int* __restrict__ cursor, int* __restrict__ csr_src) {
  int e = blockIdx.x * 256 + threadIdx.x;
  if (e < N_EDGES) {
    int pos = atomicAdd(&cursor[ei[N_EDGES + e]], 1);
    csr_src[pos] = ei[e];
  }
}

// ---------------------------------------------------------------------------
// Layer-1 aggregation v2: 1 wave per dst node, two-phase per 64-edge chunk.
// Phase 1 (64-wide): lane l gathers a_s[s_l] (32B random, 64 in flight),
//   computes 8 head-weights, stores w + src to per-wave LDS. No barrier
//   needed: per-wave LDS + wave-lockstep + explicit lgkmcnt(0).
// Phase 2 (unroll-4): ds_read_b128 of 4 src ids + 4 weights, 4 independent
//   h1 float2 gathers + fma chains. exp/a_s off the critical path.
// No max-normalization (|e| <~ 12 -> exp safe; matches softmax to fp32 rnd).
// ---------------------------------------------------------------------------
__global__ __launch_bounds__(256) void agg1_kernel(
    const int* __restrict__ indptr, const int* __restrict__ csr_src,
    const float* __restrict__ h1, const float* __restrict__ a_s,
    const float* __restrict__ a_d, const float* __restrict__ b1,
    float* __restrict__ outbuf) {
  __shared__ float wls[4][HEADS][68];  // pad 68: head rows staggered by 4 banks
  __shared__ int   sls[4][64];
  const int wave = threadIdx.x >> 6;
  const int lane = threadIdx.x & 63;
  const int node = blockIdx.x * 4 + wave;
  if (node >= N_NODES) return;
  const int head = lane >> 3;
  const int ch = lane * 2;
  float ad8[8];
#pragma unroll
  for (int h = 0; h < HEADS; ++h) ad8[h] = a_d[node * HEADS + h];
  const float ad_own = ad8[head];
  // self loop
  float e0 = a_s[node * HEADS + head] + ad_own;
  e0 = (e0 >= 0.f) ? e0 : NEG_SLOPE * e0;
  float w0 = __expf(e0);
  float2 hv = *(const float2*)&h1[node * C1 + ch];
  float ax0 = w0 * hv.x, ax1 = 0.f, ax2 = 0.f, ax3 = 0.f;
  float ay0 = w0 * hv.y, ay1 = 0.f, ay2 = 0.f, ay3 = 0.f;
  float dd0 = w0, dd1 = 0.f, dd2 = 0.f, dd3 = 0.f;
  const int start = indptr[node], end = indptr[node + 1];
  for (int j = start; j < end; j += 64) {
    const int cnt = min(64, end - j);
    if (lane < cnt) {
      int s = csr_src[j + lane];
      sls[wave][lane] = s;
      const float* asp = a_s + s * HEADS;
      float4 A = *(const float4*)asp;
      float4 B = *(const float4*)(asp + 4);
      float e;
      e = A.x + ad8[0]; e = (e >= 0.f) ? e : NEG_SLOPE * e; wls[wave][0][lane] = __expf(e);
      e = A.y + ad8[1]; e = (e >= 0.f) ? e : NEG_SLOPE * e; wls[wave][1][lane] = __expf(e);
      e = A.z + ad8[2]; e = (e >= 0.f) ? e : NEG_SLOPE * e; wls[wave][2][lane] = __expf(e);
      e = A.w + ad8[3]; e = (e >= 0.f) ? e : NEG_SLOPE * e; wls[wave][3][lane] = __expf(e);
      e = B.x + ad8[4]; e = (e >= 0.f) ? e : NEG_SLOPE * e; wls[wave][4][lane] = __expf(e);
      e = B.y + ad8[5]; e = (e >= 0.f) ? e : NEG_SLOPE * e; wls[wave][5][lane] = __expf(e);
      e = B.z + ad8[6]; e = (e >= 0.f) ? e : NEG_SLOPE * e; wls[wave][6][lane] = __expf(e);
      e = B.w + ad8[7]; e = (e >= 0.f) ? e : NEG_SLOPE * e; wls[wave][7][lane] = __expf(e);
    }
    asm volatile("s_waitcnt lgkmcnt(0)" ::: "memory");
    int i = 0;
    for (; i + 4 <= cnt; i += 4) {
      int4 sv = *(const int4*)&sls[wave][i];
      float4 wv = *(const float4*)&wls[wave][head][i];
      float2 g0 = *(const float2*)&h1[sv.x * C1 + ch];
      float2 g1 = *(const float2*)&h1[sv.y * C1 + ch];
      float2 g2 = *(const float2*)&h1[sv.z * C1 + ch];
      float2 g3 = *(const float2*)&h1[sv.w * C1 + ch];
      ax0 = fmaf(wv.x, g0.x, ax0); ay0 = fmaf(wv.x, g0.y, ay0); dd0 += wv.x;
      ax1 = fmaf(wv.y, g1.x, ax1); ay1 = fmaf(wv.y, g1.y, ay1); dd1 += wv.y;
      ax2 = fmaf(wv.z, g2.x, ax2); ay2 = fmaf(wv.z, g2.y, ay2); dd2 += wv.z;
      ax3 = fmaf(wv.w, g3.x, ax3); ay3 = fmaf(wv.w, g3.y, ay3); dd3 += wv.w;
    }
    for (; i < cnt; ++i) {
      int s = sls[wave][i];
      float w = wls[wave][head][i];
      float2 g = *(const float2*)&h1[s * C1 + ch];
      ax0 = fmaf(w, g.x, ax0); ay0 = fmaf(w, g.y, ay0); dd0 += w;
    }
  }
  float inv = 1.0f / (dd0 + dd1 + dd2 + dd3 + EPS_GAT);
  float2 bv = *(const float2*)&b1[ch];
  float ox = (ax0 + ax1 + ax2 + ax3) * inv + bv.x;
  float oy = (ay0 + ay1 + ay2 + ay3) * inv + bv.y;
  *(float2*)&outbuf[node * C1 + ch] = make_float2(ox, oy);
}

// ---------------------------------------------------------------------------
// GEMM2: h2 = elu(conv1out) @ W2  [N,128]x[128,40], fused attention dots.
// ELU applied on the fly while staging (no h_elu buffer).
// ---------------------------------------------------------------------------
__global__ __launch_bounds__(256) void gemm2_kernel(
    const float* __restrict__ conv1out, const float* __restrict__ W2,
    const float* __restrict__ att_s, const float* __restrict__ att_d,
    float* __restrict__ h2, float* __restrict__ a_s2, float* __restrict__ a_d2) {
  __shared__ float w2s[C1 * CLS];   // [k][c] 20 KB, staged once
  __shared__ float xs_t[32][132];   // [k][row], pad 132 (528B, 16B-aligned)
  const int t = threadIdx.x;
  const int r0 = blockIdx.x * 128;
  {
    const float4* wv = (const float4*)W2;
    float4* ws4 = (float4*)w2s;
#pragma unroll
    for (int i = 0; i < 5; ++i) {
      int f4 = t + i * 256;
      ws4[f4] = wv[f4];
    }
  }
  const int tx = t & 7;
  const int ty = t >> 3;
  float acc[4][5] = {};
  for (int k0 = 0; k0 < C1; k0 += 32) {
    __syncthreads();
#pragma unroll
    for (int i = 0; i < 4; ++i) {
      int f4 = t + i * 256;
      int row = f4 >> 3;
      int k4 = (f4 & 7) * 4;
      int grow = min(r0 + row, N_NODES - 1);
      float4 v = *(const float4*)&conv1out[grow * C1 + k0 + k4];
      v.x = (v.x > 0.f) ? v.x : (__expf(v.x) - 1.0f);
      v.y = (v.y > 0.f) ? v.y : (__expf(v.y) - 1.0f);
      v.z = (v.z > 0.f) ? v.z : (__expf(v.z) - 1.0f);
      v.w = (v.w > 0.f) ? v.w : (__expf(v.w) - 1.0f);
      xs_t[k4][row] = v.x; xs_t[k4 + 1][row] = v.y;
      xs_t[k4 + 2][row] = v.z; xs_t[k4 + 3][row] = v.w;
    }
    __syncthreads();
#pragma unroll
    for (int kk = 0; kk < 32; ++kk) {
      float4 av = *(float4*)&xs_t[kk][ty * 4];
      float a[4] = {av.x, av.y, av.z, av.w};
      float b[5];
      const float* wrow = &w2s[(k0 + kk) * CLS + tx];
#pragma unroll
      for (int j = 0; j < 5; ++j) b[j] = wrow[8 * j];
#pragma unroll
      for (int i = 0; i < 4; ++i)
#pragma unroll
        for (int j = 0; j < 5; ++j) acc[i][j] = fmaf(a[i], b[j], acc[i][j]);
    }
  }
  float asc[5], adc[5];
#pragma unroll
  for (int j = 0; j < 5; ++j) { asc[j] = att_s[tx + 8 * j]; adc[j] = att_d[tx + 8 * j]; }
#pragma unroll
  for (int i = 0; i < 4; ++i) {
    int row = r0 + ty * 4 + i;
    float ps = 0.f, pd = 0.f;
#pragma unroll
    for (int j = 0; j < 5; ++j) {
      ps += acc[i][j] * asc[j];
      pd += acc[i][j] * adc[j];
    }
    ps += __shfl_xor(ps, 1); ps += __shfl_xor(ps, 2); ps += __shfl_xor(ps, 4);
    pd += __shfl_xor(pd, 1); pd += __shfl_xor(pd, 2); pd += __shfl_xor(pd, 4);
    if (row < N_NODES) {
#pragma unroll
      for (int j = 0; j < 5; ++j) h2[row * CLS + tx + 8 * j] = acc[i][j];
      if (tx == 0) { a_s2[row] = ps; a_d2[row] = pd; }
    }
  }
}

// ---------------------------------------------------------------------------
// Layer-2 aggregation v2 + bias + log_softmax. Same two-phase structure.
// ---------------------------------------------------------------------------
__global__ __launch_bounds__(256) void agg2_kernel(
    const int* __restrict__ indptr, const int* __restrict__ csr_src,
    const float* __restrict__ h2, const float* __restrict__ a_s,
    const float* __restrict__ a_d, const float* __restrict__ b2,
    float* __restrict__ out) {
  __shared__ float wls[4][64];
  __shared__ int   sls[4][64];
  const int wave = threadIdx.x >> 6;
  const int lane = threadIdx.x & 63;
  const int node = blockIdx.x * 4 + wave;
  if (node >= N_NODES) return;
  const bool act = lane < CLS;
  const float ad = a_d[node];
  float e0 = a_s[node] + ad;
  e0 = (e0 >= 0.f) ? e0 : NEG_SLOPE * e0;
  float w0 = __expf(e0);
  float a0 = act ? w0 * h2[node * CLS + lane] : 0.f;
  float a1 = 0.f, a2 = 0.f, a3 = 0.f;
  float dd0 = w0, dd1 = 0.f, dd2 = 0.f, dd3 = 0.f;
  const int start = indptr[node], end = indptr[node + 1];
  for (int j = start; j < end; j += 64) {
    const int cnt = min(64, end - j);
    if (lane < cnt) {
      int s = csr_src[j + lane];
      sls[wave][lane] = s;
      float e = a_s[s] + ad;
      e = (e >= 0.f) ? e : NEG_SLOPE * e;
      wls[wave][lane] = __expf(e);
    }
    asm volatile("s_waitcnt lgkmcnt(0)" ::: "memory");
    int i = 0;
    for (; i + 4 <= cnt; i += 4) {
      int4 sv = *(const int4*)&sls[wave][i];
      float4 wv = *(const float4*)&wls[wave][i];
      float g0 = act ? h2[sv.x * CLS + lane] : 0.f;
      float g1 = act ? h2[sv.y * CLS + lane] : 0.f;
      float g2 = act ? h2[sv.z * CLS + lane] : 0.f;
      float g3 = act ? h2[sv.w * CLS + lane] : 0.f;
      a0 = fmaf(wv.x, g0, a0); dd0 += wv.x;
      a1 = fmaf(wv.y, g1, a1); dd1 += wv.y;
      a2 = fmaf(wv.z, g2, a2); dd2 += wv.z;
      a3 = fmaf(wv.w, g3, a3); dd3 += wv.w;
    }
    for (; i < cnt; ++i) {
      int s = sls[wave][i];
      float w = wls[wave][i];
      float g = act ? h2[s * CLS + lane] : 0.f;
      a0 = fmaf(w, g, a0); dd0 += w;
    }
  }
  float x2 = (a0 + a1 + a2 + a3) / (dd0 + dd1 + dd2 + dd3 + EPS_GAT) + (act ? b2[lane] : 0.f);
  float xm = act ? x2 : -__builtin_inff();
  for (int off = 32; off; off >>= 1) xm = fmaxf(xm, __shfl_xor(xm, off));
  float p = act ? __expf(x2 - xm) : 0.f;
  float ps = p;
  for (int off = 32; off; off >>= 1) ps += __shfl_xor(ps, off);
  float ls = x2 - xm - __logf(ps);
  if (act) out[node * CLS + lane] = ls;
}

// ---------------------------------------------------------------------------
extern "C" void kernel_launch(void* const* d_in, const int* in_sizes, int n_in,
                              void* d_out, int out_size, void* d_ws, size_t ws_size,
                              hipStream_t stream) {
  const float* x        = (const float*)d_in[0];
  const int*   ei       = (const int*)d_in[1];
  const float* W1       = (const float*)d_in[3];
  const float* att_src1 = (const float*)d_in[4];
  const float* att_dst1 = (const float*)d_in[5];
  const float* b1       = (const float*)d_in[6];
  const float* W2       = (const float*)d_in[7];
  const float* att_src2 = (const float*)d_in[8];
  const float* att_dst2 = (const float*)d_in[9];
  const float* b2       = (const float*)d_in[10];

  float* outf    = (float*)d_out;                  // [N*40] log_softmax
  float* outconv = outf + (size_t)N_NODES * CLS;   // [N*128] conv1 output (pre-ELU)

  // workspace layout (4-byte units), ~42 MB total
  float* wsf = (float*)d_ws;
  size_t o = 0;
  float* h1    = wsf + o; o += (size_t)N_NODES * C1;    // 6.4M
  float* a_s1  = wsf + o; o += (size_t)N_NODES * HEADS; // 0.4M
  float* a_d1  = wsf + o; o += (size_t)N_NODES * HEADS;
  float* h2    = wsf + o; o += (size_t)N_NODES * CLS;   // 2M
  float* a_s2  = wsf + o; o += N_NODES;
  float* a_d2  = wsf + o; o += N_NODES;
  int* deg     = (int*)(wsf + o); o += N_NODES;
  int* indptr  = (int*)(wsf + o); o += N_NODES + 4;
  int* cursor  = (int*)(wsf + o); o += N_NODES;
  int* csr_src = (int*)(wsf + o); o += N_EDGES;
  (void)ws_size;

  const int eb = (N_EDGES + 255) / 256;
  const int nb = (N_NODES + 255) / 256;

  zero_kernel<<<nb, 256, 0, stream>>>(deg);
  gemm1_kernel<<<(N_NODES + 63) / 64, 256, 0, stream>>>(x, W1, att_src1, att_dst1,
                                                        h1, a_s1, a_d1);
  hist_kernel<<<eb, 256, 0, stream>>>(ei, deg);
  scan_kernel<<<1, 1024, 0, stream>>>(deg, indptr, cursor);
  scatter_kernel<<<eb, 256, 0, stream>>>(ei, cursor, csr_src);
  agg1_kernel<<<(N_NODES + 3) / 4, 256, 0, stream>>>(indptr, csr_src, h1, a_s1, a_d1,
                                                     b1, outconv);
  gemm2_kernel<<<(N_NODES + 127) / 128, 256, 0, stream>>>(outconv, W2, att_src2, att_dst2,
                                                          h2, a_s2, a_d2);
  agg2_kernel<<<(N_NODES + 3) / 4, 256, 0, stream>>>(indptr, csr_src, h2, a_s2, a_d2,
                                                     b2, outf);
}

// Round 8
// 414.624 us; speedup vs baseline: 1.2380x; 1.2380x over previous
//
#include <hip/hip_runtime.h>
#include <hip/hip_bf16.h>

#define N_NODES 50000
#define N_EDGES 1000000
#define F_IN 256
#define C1 128      // HEADS*HID
#define HEADS 8
#define CLS 40
#define NEG_SLOPE 0.2f
#define EPS_GAT 1e-16f
#define NB_SCAN 196  // ceil(N_NODES/256)

// ---------------------------------------------------------------------------
// GEMM1: h1 = x @ W1  [N,256]x[256,128], fused attention dots.
// block = 256 threads, tile = 64 rows x 128 cols, K chunks of 32.
// thread micro-tile 8x4 (tx = col-group of 4, ty = row-group of 8).
// ---------------------------------------------------------------------------
__global__ __launch_bounds__(256) void gemm1_kernel(
    const float* __restrict__ x, const float* __restrict__ W1,
    const float* __restrict__ att_s, const float* __restrict__ att_d,
    float* __restrict__ h1, float* __restrict__ a_s1, float* __restrict__ a_d1) {
  __shared__ float xs_t[32][72];   // [k][row64], pad 72 (288B, 16B-aligned)
  __shared__ float ws[32][128];    // [k][col]
  const int t = threadIdx.x;
  const int tx = t & 31, ty = t >> 5;   // ty in 0..7
  const int r0 = blockIdx.x * 64;
  float acc[8][4] = {};
  for (int k0 = 0; k0 < F_IN; k0 += 32) {
    __syncthreads();
    const float4* Wv = (const float4*)(W1 + k0 * C1);
#pragma unroll
    for (int i = 0; i < 4; ++i) {
      int f4 = t + i * 256;
      *(float4*)&ws[f4 >> 5][(f4 & 31) * 4] = Wv[f4];
    }
#pragma unroll
    for (int i = 0; i < 2; ++i) {
      int f4 = t + i * 256;
      int rr = f4 >> 3;              // 8 float4 per row
      int k4 = (f4 & 7) * 4;
      int grow = min(r0 + rr, N_NODES - 1);
      float4 v = *(const float4*)&x[grow * F_IN + k0 + k4];
      xs_t[k4][rr] = v.x; xs_t[k4 + 1][rr] = v.y;
      xs_t[k4 + 2][rr] = v.z; xs_t[k4 + 3][rr] = v.w;
    }
    __syncthreads();
#pragma unroll
    for (int kk = 0; kk < 32; ++kk) {
      float4 a0v = *(float4*)&xs_t[kk][ty * 8];
      float4 a1v = *(float4*)&xs_t[kk][ty * 8 + 4];
      float4 bv  = *(float4*)&ws[kk][tx * 4];
      float a[8] = {a0v.x, a0v.y, a0v.z, a0v.w, a1v.x, a1v.y, a1v.z, a1v.w};
      float b[4] = {bv.x, bv.y, bv.z, bv.w};
#pragma unroll
      for (int i = 0; i < 8; ++i)
#pragma unroll
        for (int j = 0; j < 4; ++j) acc[i][j] = fmaf(a[i], b[j], acc[i][j]);
    }
  }
  float as_c[4], ad_c[4];
#pragma unroll
  for (int j = 0; j < 4; ++j) { as_c[j] = att_s[tx * 4 + j]; ad_c[j] = att_d[tx * 4 + j]; }
  const int head = tx >> 2;
#pragma unroll
  for (int i = 0; i < 8; ++i) {
    int row = r0 + ty * 8 + i;
    float ps = acc[i][0] * as_c[0] + acc[i][1] * as_c[1] + acc[i][2] * as_c[2] + acc[i][3] * as_c[3];
    float pd = acc[i][0] * ad_c[0] + acc[i][1] * ad_c[1] + acc[i][2] * ad_c[2] + acc[i][3] * ad_c[3];
    ps += __shfl_xor(ps, 1); ps += __shfl_xor(ps, 2);
    pd += __shfl_xor(pd, 1); pd += __shfl_xor(pd, 2);
    if (row < N_NODES) {
      *(float4*)&h1[row * C1 + tx * 4] = make_float4(acc[i][0], acc[i][1], acc[i][2], acc[i][3]);
      if ((tx & 3) == 0) { a_s1[row * HEADS + head] = ps; a_d1[row * HEADS + head] = pd; }
    }
  }
}

// ---------------------------------------------------------------------------
// CSR build: zero, histogram, two-level parallel scan, scatter.
// ---------------------------------------------------------------------------
__global__ void zero_kernel(int* __restrict__ deg) {
  int i = blockIdx.x * 256 + threadIdx.x;
  if (i < N_NODES) deg[i] = 0;
}

__global__ void hist_kernel(const int* __restrict__ ei, int* __restrict__ deg) {
  int e = blockIdx.x * 256 + threadIdx.x;
  if (e < N_EDGES) atomicAdd(&deg[ei[N_EDGES + e]], 1);
}

// per-256-node chunk sums: wave shfl reduce + LDS combine
__global__ __launch_bounds__(256) void blocksum_kernel(const int* __restrict__ deg,
                                                       int* __restrict__ bsum) {
  __shared__ int wsum[4];
  const int t = threadIdx.x;
  const int i = blockIdx.x * 256 + t;
  int v = (i < N_NODES) ? deg[i] : 0;
#pragma unroll
  for (int off = 32; off; off >>= 1) v += __shfl_xor(v, off);
  if ((t & 63) == 0) wsum[t >> 6] = v;
  __syncthreads();
  if (t == 0) bsum[blockIdx.x] = wsum[0] + wsum[1] + wsum[2] + wsum[3];
}

// scan the 196 block sums (1 small block) -> exclusive block prefixes
__global__ __launch_bounds__(256) void scanblocks_kernel(const int* __restrict__ bsum,
                                                         int* __restrict__ bpre,
                                                         int* __restrict__ indptr) {
  __shared__ int sm[256];
  const int t = threadIdx.x;
  int v = (t < NB_SCAN) ? bsum[t] : 0;
  sm[t] = v;
  __syncthreads();
  for (int off = 1; off < 256; off <<= 1) {
    int add = (t >= off) ? sm[t - off] : 0;
    __syncthreads();
    sm[t] += add;
    __syncthreads();
  }
  if (t < NB_SCAN) bpre[t] = sm[t] - v;       // exclusive prefix
  if (t == 0) indptr[N_NODES] = N_EDGES;      // degree sum == E by construction
}

// per-block local scan + block prefix -> indptr, cursor
__global__ __launch_bounds__(256) void writeptr_kernel(const int* __restrict__ deg,
                                                       const int* __restrict__ bpre,
                                                       int* __restrict__ indptr,
                                                       int* __restrict__ cursor) {
  __shared__ int sm[256];
  const int t = threadIdx.x;
  const int i = blockIdx.x * 256 + t;
  int v = (i < N_NODES) ? deg[i] : 0;
  sm[t] = v;
  __syncthreads();
  for (int off = 1; off < 256; off <<= 1) {
    int add = (t >= off) ? sm[t - off] : 0;
    __syncthreads();
    sm[t] += add;
    __syncthreads();
  }
  if (i < N_NODES) {
    int p = bpre[blockIdx.x] + sm[t] - v;     // exclusive
    indptr[i] = p;
    cursor[i] = p;
  }
}

__global__ void scatter_kernel(const int* __restrict__ ei,
                               int* __restrict__ cursor, int* __restrict__ csr_src) {
  int e = blockIdx.x * 256 + threadIdx.x;
  if (e < N_EDGES) {
    int pos = atomicAdd(&cursor[ei[N_EDGES + e]], 1);
    csr_src[pos] = ei[e];
  }
}

// ---------------------------------------------------------------------------
// Layer-1 aggregation v2: 1 wave per dst node, two-phase per 64-edge chunk.
// Phase 1 (64-wide): lane l gathers a_s[s_l], computes 8 head-weights -> LDS.
// Phase 2 (unroll-4): b128 reads of ids+weights, 4 independent h1 gathers.
// No max-normalization (|e| <~ 12 -> exp safe; matches softmax to fp32 rnd).
// ---------------------------------------------------------------------------
__global__ __launch_bounds__(256) void agg1_kernel(
    const int* __restrict__ indptr, const int* __restrict__ csr_src,
    const float* __restrict__ h1, const float* __restrict__ a_s,
    const float* __restrict__ a_d, const float* __restrict__ b1,
    float* __restrict__ outbuf) {
  __shared__ float wls[4][HEADS][68];  // pad 68: head rows staggered by 4 banks
  __shared__ int   sls[4][64];
  const int wave = threadIdx.x >> 6;
  const int lane = threadIdx.x & 63;
  const int node = blockIdx.x * 4 + wave;
  if (node >= N_NODES) return;
  const int head = lane >> 3;
  const int ch = lane * 2;
  float ad8[8];
#pragma unroll
  for (int h = 0; h < HEADS; ++h) ad8[h] = a_d[node * HEADS + h];
  const float ad_own = ad8[head];
  float e0 = a_s[node * HEADS + head] + ad_own;
  e0 = (e0 >= 0.f) ? e0 : NEG_SLOPE * e0;
  float w0 = __expf(e0);
  float2 hv = *(const float2*)&h1[node * C1 + ch];
  float ax0 = w0 * hv.x, ax1 = 0.f, ax2 = 0.f, ax3 = 0.f;
  float ay0 = w0 * hv.y, ay1 = 0.f, ay2 = 0.f, ay3 = 0.f;
  float dd0 = w0, dd1 = 0.f, dd2 = 0.f, dd3 = 0.f;
  const int start = indptr[node], end = indptr[node + 1];
  for (int j = start; j < end; j += 64) {
    const int cnt = min(64, end - j);
    if (lane < cnt) {
      int s = csr_src[j + lane];
      sls[wave][lane] = s;
      const float* asp = a_s + s * HEADS;
      float4 A = *(const float4*)asp;
      float4 B = *(const float4*)(asp + 4);
      float e;
      e = A.x + ad8[0]; e = (e >= 0.f) ? e : NEG_SLOPE * e; wls[wave][0][lane] = __expf(e);
      e = A.y + ad8[1]; e = (e >= 0.f) ? e : NEG_SLOPE * e; wls[wave][1][lane] = __expf(e);
      e = A.z + ad8[2]; e = (e >= 0.f) ? e : NEG_SLOPE * e; wls[wave][2][lane] = __expf(e);
      e = A.w + ad8[3]; e = (e >= 0.f) ? e : NEG_SLOPE * e; wls[wave][3][lane] = __expf(e);
      e = B.x + ad8[4]; e = (e >= 0.f) ? e : NEG_SLOPE * e; wls[wave][4][lane] = __expf(e);
      e = B.y + ad8[5]; e = (e >= 0.f) ? e : NEG_SLOPE * e; wls[wave][5][lane] = __expf(e);
      e = B.z + ad8[6]; e = (e >= 0.f) ? e : NEG_SLOPE * e; wls[wave][6][lane] = __expf(e);
      e = B.w + ad8[7]; e = (e >= 0.f) ? e : NEG_SLOPE * e; wls[wave][7][lane] = __expf(e);
    }
    asm volatile("s_waitcnt lgkmcnt(0)" ::: "memory");
    int i = 0;
    for (; i + 4 <= cnt; i += 4) {
      int4 sv = *(const int4*)&sls[wave][i];
      float4 wv = *(const float4*)&wls[wave][head][i];
      float2 g0 = *(const float2*)&h1[sv.x * C1 + ch];
      float2 g1 = *(const float2*)&h1[sv.y * C1 + ch];
      float2 g2 = *(const float2*)&h1[sv.z * C1 + ch];
      float2 g3 = *(const float2*)&h1[sv.w * C1 + ch];
      ax0 = fmaf(wv.x, g0.x, ax0); ay0 = fmaf(wv.x, g0.y, ay0); dd0 += wv.x;
      ax1 = fmaf(wv.y, g1.x, ax1); ay1 = fmaf(wv.y, g1.y, ay1); dd1 += wv.y;
      ax2 = fmaf(wv.z, g2.x, ax2); ay2 = fmaf(wv.z, g2.y, ay2); dd2 += wv.z;
      ax3 = fmaf(wv.w, g3.x, ax3); ay3 = fmaf(wv.w, g3.y, ay3); dd3 += wv.w;
    }
    for (; i < cnt; ++i) {
      int s = sls[wave][i];
      float w = wls[wave][head][i];
      float2 g = *(const float2*)&h1[s * C1 + ch];
      ax0 = fmaf(w, g.x, ax0); ay0 = fmaf(w, g.y, ay0); dd0 += w;
    }
  }
  float inv = 1.0f / (dd0 + dd1 + dd2 + dd3 + EPS_GAT);
  float2 bv = *(const float2*)&b1[ch];
  float ox = (ax0 + ax1 + ax2 + ax3) * inv + bv.x;
  float oy = (ay0 + ay1 + ay2 + ay3) * inv + bv.y;
  *(float2*)&outbuf[node * C1 + ch] = make_float2(ox, oy);
}

// ---------------------------------------------------------------------------
// GEMM2: h2 = elu(conv1out) @ W2  [N,128]x[128,40], fused attention dots.
// ---------------------------------------------------------------------------
__global__ __launch_bounds__(256) void gemm2_kernel(
    const float* __restrict__ conv1out, const float* __restrict__ W2,
    const float* __restrict__ att_s, const float* __restrict__ att_d,
    float* __restrict__ h2, float* __restrict__ a_s2, float* __restrict__ a_d2) {
  __shared__ float w2s[C1 * CLS];   // 20 KB, staged once
  __shared__ float xs_t[32][132];   // [k][row], pad 132
  const int t = threadIdx.x;
  const int r0 = blockIdx.x * 128;
  {
    const float4* wv = (const float4*)W2;
    float4* ws4 = (float4*)w2s;
#pragma unroll
    for (int i = 0; i < 5; ++i) {
      int f4 = t + i * 256;
      ws4[f4] = wv[f4];
    }
  }
  const int tx = t & 7;
  const int ty = t >> 3;
  float acc[4][5] = {};
  for (int k0 = 0; k0 < C1; k0 += 32) {
    __syncthreads();
#pragma unroll
    for (int i = 0; i < 4; ++i) {
      int f4 = t + i * 256;
      int row = f4 >> 3;
      int k4 = (f4 & 7) * 4;
      int grow = min(r0 + row, N_NODES - 1);
      float4 v = *(const float4*)&conv1out[grow * C1 + k0 + k4];
      v.x = (v.x > 0.f) ? v.x : (__expf(v.x) - 1.0f);
      v.y = (v.y > 0.f) ? v.y : (__expf(v.y) - 1.0f);
      v.z = (v.z > 0.f) ? v.z : (__expf(v.z) - 1.0f);
      v.w = (v.w > 0.f) ? v.w : (__expf(v.w) - 1.0f);
      xs_t[k4][row] = v.x; xs_t[k4 + 1][row] = v.y;
      xs_t[k4 + 2][row] = v.z; xs_t[k4 + 3][row] = v.w;
    }
    __syncthreads();
#pragma unroll
    for (int kk = 0; kk < 32; ++kk) {
      float4 av = *(float4*)&xs_t[kk][ty * 4];
      float a[4] = {av.x, av.y, av.z, av.w};
      float b[5];
      const float* wrow = &w2s[(k0 + kk) * CLS + tx];
#pragma unroll
      for (int j = 0; j < 5; ++j) b[j] = wrow[8 * j];
#pragma unroll
      for (int i = 0; i < 4; ++i)
#pragma unroll
        for (int j = 0; j < 5; ++j) acc[i][j] = fmaf(a[i], b[j], acc[i][j]);
    }
  }
  float asc[5], adc[5];
#pragma unroll
  for (int j = 0; j < 5; ++j) { asc[j] = att_s[tx + 8 * j]; adc[j] = att_d[tx + 8 * j]; }
#pragma unroll
  for (int i = 0; i < 4; ++i) {
    int row = r0 + ty * 4 + i;
    float ps = 0.f, pd = 0.f;
#pragma unroll
    for (int j = 0; j < 5; ++j) {
      ps += acc[i][j] * asc[j];
      pd += acc[i][j] * adc[j];
    }
    ps += __shfl_xor(ps, 1); ps += __shfl_xor(ps, 2); ps += __shfl_xor(ps, 4);
    pd += __shfl_xor(pd, 1); pd += __shfl_xor(pd, 2); pd += __shfl_xor(pd, 4);
    if (row < N_NODES) {
#pragma unroll
      for (int j = 0; j < 5; ++j) h2[row * CLS + tx + 8 * j] = acc[i][j];
      if (tx == 0) { a_s2[row] = ps; a_d2[row] = pd; }
    }
  }
}

// ---------------------------------------------------------------------------
// Layer-2 aggregation v2 + bias + log_softmax. Two-phase structure.
// ---------------------------------------------------------------------------
__global__ __launch_bounds__(256) void agg2_kernel(
    const int* __restrict__ indptr, const int* __restrict__ csr_src,
    const float* __restrict__ h2, const float* __restrict__ a_s,
    const float* __restrict__ a_d, const float* __restrict__ b2,
    float* __restrict__ out) {
  __shared__ float wls[4][64];
  __shared__ int   sls[4][64];
  const int wave = threadIdx.x >> 6;
  const int lane = threadIdx.x & 63;
  const int node = blockIdx.x * 4 + wave;
  if (node >= N_NODES) return;
  const bool act = lane < CLS;
  const float ad = a_d[node];
  float e0 = a_s[node] + ad;
  e0 = (e0 >= 0.f) ? e0 : NEG_SLOPE * e0;
  float w0 = __expf(e0);
  float a0 = act ? w0 * h2[node * CLS + lane] : 0.f;
  float a1 = 0.f, a2 = 0.f, a3 = 0.f;
  float dd0 = w0, dd1 = 0.f, dd2 = 0.f, dd3 = 0.f;
  const int start = indptr[node], end = indptr[node + 1];
  for (int j = start; j < end; j += 64) {
    const int cnt = min(64, end - j);
    if (lane < cnt) {
      int s = csr_src[j + lane];
      sls[wave][lane] = s;
      float e = a_s[s] + ad;
      e = (e >= 0.f) ? e : NEG_SLOPE * e;
      wls[wave][lane] = __expf(e);
    }
    asm volatile("s_waitcnt lgkmcnt(0)" ::: "memory");
    int i = 0;
    for (; i + 4 <= cnt; i += 4) {
      int4 sv = *(const int4*)&sls[wave][i];
      float4 wv = *(const float4*)&wls[wave][i];
      float g0 = act ? h2[sv.x * CLS + lane] : 0.f;
      float g1 = act ? h2[sv.y * CLS + lane] : 0.f;
      float g2 = act ? h2[sv.z * CLS + lane] : 0.f;
      float g3 = act ? h2[sv.w * CLS + lane] : 0.f;
      a0 = fmaf(wv.x, g0, a0); dd0 += wv.x;
      a1 = fmaf(wv.y, g1, a1); dd1 += wv.y;
      a2 = fmaf(wv.z, g2, a2); dd2 += wv.z;
      a3 = fmaf(wv.w, g3, a3); dd3 += wv.w;
    }
    for (; i < cnt; ++i) {
      int s = sls[wave][i];
      float w = wls[wave][i];
      float g = act ? h2[s * CLS + lane] : 0.f;
      a0 = fmaf(w, g, a0); dd0 += w;
    }
  }
  float x2 = (a0 + a1 + a2 + a3) / (dd0 + dd1 + dd2 + dd3 + EPS_GAT) + (act ? b2[lane] : 0.f);
  float xm = act ? x2 : -__builtin_inff();
  for (int off = 32; off; off >>= 1) xm = fmaxf(xm, __shfl_xor(xm, off));
  float p = act ? __expf(x2 - xm) : 0.f;
  float ps = p;
  for (int off = 32; off; off >>= 1) ps += __shfl_xor(ps, off);
  float ls = x2 - xm - __logf(ps);
  if (act) out[node * CLS + lane] = ls;
}

// ---------------------------------------------------------------------------
extern "C" void kernel_launch(void* const* d_in, const int* in_sizes, int n_in,
                              void* d_out, int out_size, void* d_ws, size_t ws_size,
                              hipStream_t stream) {
  const float* x        = (const float*)d_in[0];
  const int*   ei       = (const int*)d_in[1];
  const float* W1       = (const float*)d_in[3];
  const float* att_src1 = (const float*)d_in[4];
  const float* att_dst1 = (const float*)d_in[5];
  const float* b1       = (const float*)d_in[6];
  const float* W2       = (const float*)d_in[7];
  const float* att_src2 = (const float*)d_in[8];
  const float* att_dst2 = (const float*)d_in[9];
  const float* b2       = (const float*)d_in[10];

  float* outf    = (float*)d_out;                  // [N*40] log_softmax
  float* outconv = outf + (size_t)N_NODES * CLS;   // [N*128] conv1 output (pre-ELU)

  // workspace layout (4-byte units), ~42 MB total
  float* wsf = (float*)d_ws;
  size_t o = 0;
  float* h1    = wsf + o; o += (size_t)N_NODES * C1;    // 6.4M
  float* a_s1  = wsf + o; o += (size_t)N_NODES * HEADS; // 0.4M
  float* a_d1  = wsf + o; o += (size_t)N_NODES * HEADS;
  float* h2    = wsf + o; o += (size_t)N_NODES * CLS;   // 2M
  float* a_s2  = wsf + o; o += N_NODES;
  float* a_d2  = wsf + o; o += N_NODES;
  int* deg     = (int*)(wsf + o); o += N_NODES;
  int* indptr  = (int*)(wsf + o); o += N_NODES + 4;
  int* cursor  = (int*)(wsf + o); o += N_NODES;
  int* bsum    = (int*)(wsf + o); o += 256;
  int* bpre    = (int*)(wsf + o); o += 256;
  int* csr_src = (int*)(wsf + o); o += N_EDGES;
  (void)ws_size;

  const int eb = (N_EDGES + 255) / 256;
  const int nb = (N_NODES + 255) / 256;

  zero_kernel<<<nb, 256, 0, stream>>>(deg);
  gemm1_kernel<<<(N_NODES + 63) / 64, 256, 0, stream>>>(x, W1, att_src1, att_dst1,
                                                        h1, a_s1, a_d1);
  hist_kernel<<<eb, 256, 0, stream>>>(ei, deg);
  blocksum_kernel<<<NB_SCAN, 256, 0, stream>>>(deg, bsum);
  scanblocks_kernel<<<1, 256, 0, stream>>>(bsum, bpre, indptr);
  writeptr_kernel<<<NB_SCAN, 256, 0, stream>>>(deg, bpre, indptr, cursor);
  scatter_kernel<<<eb, 256, 0, stream>>>(ei, cursor, csr_src);
  agg1_kernel<<<(N_NODES + 3) / 4, 256, 0, stream>>>(indptr, csr_src, h1, a_s1, a_d1,
                                                     b1, outconv);
  gemm2_kernel<<<(N_NODES + 127) / 128, 256, 0, stream>>>(outconv, W2, att_src2, att_dst2,
                                                          h2, a_s2, a_d2);
  agg2_kernel<<<(N_NODES + 3) / 4, 256, 0, stream>>>(indptr, csr_src, h2, a_s2, a_d2,
                                                     b2, outf);
}

// Round 10
// 347.282 us; speedup vs baseline: 1.4781x; 1.1939x over previous
//
#include <hip/hip_runtime.h>
#include <hip/hip_bf16.h>

#define N_NODES 50000
#define N_EDGES 1000000
#define F_IN 256
#define C1 128      // HEADS*HID
#define HEADS 8
#define CLS 40
#define NEG_SLOPE 0.2f
#define EPS_GAT 1e-16f
#define NBKT 196        // buckets of 256 nodes: dst>>8
#define ECH 4096        // edges per block in bucket passes
#define NBLK_A 245      // ceil(E/ECH)

// ---------------------------------------------------------------------------
// GEMM1: h1 = x @ W1  [N,256]x[256,128], fused attention dots. (unchanged)
// ---------------------------------------------------------------------------
__global__ __launch_bounds__(256) void gemm1_kernel(
    const float* __restrict__ x, const float* __restrict__ W1,
    const float* __restrict__ att_s, const float* __restrict__ att_d,
    float* __restrict__ h1, float* __restrict__ a_s1, float* __restrict__ a_d1) {
  __shared__ float xs_t[32][72];   // [k][row64], pad 72
  __shared__ float ws[32][128];    // [k][col]
  const int t = threadIdx.x;
  const int tx = t & 31, ty = t >> 5;
  const int r0 = blockIdx.x * 64;
  float acc[8][4] = {};
  for (int k0 = 0; k0 < F_IN; k0 += 32) {
    __syncthreads();
    const float4* Wv = (const float4*)(W1 + k0 * C1);
#pragma unroll
    for (int i = 0; i < 4; ++i) {
      int f4 = t + i * 256;
      *(float4*)&ws[f4 >> 5][(f4 & 31) * 4] = Wv[f4];
    }
#pragma unroll
    for (int i = 0; i < 2; ++i) {
      int f4 = t + i * 256;
      int rr = f4 >> 3;
      int k4 = (f4 & 7) * 4;
      int grow = min(r0 + rr, N_NODES - 1);
      float4 v = *(const float4*)&x[grow * F_IN + k0 + k4];
      xs_t[k4][rr] = v.x; xs_t[k4 + 1][rr] = v.y;
      xs_t[k4 + 2][rr] = v.z; xs_t[k4 + 3][rr] = v.w;
    }
    __syncthreads();
#pragma unroll
    for (int kk = 0; kk < 32; ++kk) {
      float4 a0v = *(float4*)&xs_t[kk][ty * 8];
      float4 a1v = *(float4*)&xs_t[kk][ty * 8 + 4];
      float4 bv  = *(float4*)&ws[kk][tx * 4];
      float a[8] = {a0v.x, a0v.y, a0v.z, a0v.w, a1v.x, a1v.y, a1v.z, a1v.w};
      float b[4] = {bv.x, bv.y, bv.z, bv.w};
#pragma unroll
      for (int i = 0; i < 8; ++i)
#pragma unroll
        for (int j = 0; j < 4; ++j) acc[i][j] = fmaf(a[i], b[j], acc[i][j]);
    }
  }
  float as_c[4], ad_c[4];
#pragma unroll
  for (int j = 0; j < 4; ++j) { as_c[j] = att_s[tx * 4 + j]; ad_c[j] = att_d[tx * 4 + j]; }
  const int head = tx >> 2;
#pragma unroll
  for (int i = 0; i < 8; ++i) {
    int row = r0 + ty * 8 + i;
    float ps = acc[i][0] * as_c[0] + acc[i][1] * as_c[1] + acc[i][2] * as_c[2] + acc[i][3] * as_c[3];
    float pd = acc[i][0] * ad_c[0] + acc[i][1] * ad_c[1] + acc[i][2] * ad_c[2] + acc[i][3] * ad_c[3];
    ps += __shfl_xor(ps, 1); ps += __shfl_xor(ps, 2);
    pd += __shfl_xor(pd, 1); pd += __shfl_xor(pd, 2);
    if (row < N_NODES) {
      *(float4*)&h1[row * C1 + tx * 4] = make_float4(acc[i][0], acc[i][1], acc[i][2], acc[i][3]);
      if ((tx & 3) == 0) { a_s1[row * HEADS + head] = ps; a_d1[row * HEADS + head] = pd; }
    }
  }
}

// ---------------------------------------------------------------------------
// CSR build v3: bucketed (bucket = dst>>8, 196 buckets x 256 nodes).
// Replaces zero/hist/blocksum/scanblocks/writeptr/scatter: no 1M-way random
// atomics, writes confined to contiguous/bucket-local regions.
// ---------------------------------------------------------------------------
__global__ void zero256_kernel(int* __restrict__ bktcount) {
  bktcount[threadIdx.x] = 0;
}

// A1: per-block LDS histogram of dst>>8, one global atomic per (block,bucket)
__global__ __launch_bounds__(256) void bucket_count_kernel(const int* __restrict__ ei,
                                                           int* __restrict__ bktcount) {
  __shared__ int c[256];
  const int t = threadIdx.x;
  c[t] = 0;
  __syncthreads();
  const int e0 = blockIdx.x * ECH;
#pragma unroll
  for (int i = 0; i < ECH / 256; ++i) {
    int e = e0 + t + i * 256;
    if (e < N_EDGES) atomicAdd(&c[ei[N_EDGES + e] >> 8], 1);
  }
  __syncthreads();
  if (c[t]) atomicAdd(&bktcount[t], c[t]);
}

// A2: scan 196 bucket counts -> bases; seed cursors; indptr[N]=E
__global__ __launch_bounds__(256) void bucket_scan_kernel(const int* __restrict__ bktcount,
                                                          int* __restrict__ bktbase,
                                                          int* __restrict__ bktcursor,
                                                          int* __restrict__ indptr) {
  __shared__ int sm[256];
  const int t = threadIdx.x;
  int v = (t < NBKT) ? bktcount[t] : 0;
  sm[t] = v;
  __syncthreads();
  for (int off = 1; off < 256; off <<= 1) {
    int add = (t >= off) ? sm[t - off] : 0;
    __syncthreads();
    sm[t] += add;
    __syncthreads();
  }
  int excl = sm[t] - v;
  bktbase[t] = excl;
  bktcursor[t] = excl;
  if (t == 0) indptr[N_NODES] = N_EDGES;
}

// A3: scatter edges into bucket regions; packed = src<<8 | (dst&255)
__global__ __launch_bounds__(256) void bucket_scatter_kernel(const int* __restrict__ ei,
                                                             int* __restrict__ bktcursor,
                                                             int* __restrict__ bktbuf) {
  __shared__ int c[256], c2[256], base[256];
  const int t = threadIdx.x;
  c[t] = 0; c2[t] = 0;
  __syncthreads();
  const int e0 = blockIdx.x * ECH;
#pragma unroll
  for (int i = 0; i < ECH / 256; ++i) {
    int e = e0 + t + i * 256;
    if (e < N_EDGES) atomicAdd(&c[ei[N_EDGES + e] >> 8], 1);
  }
  __syncthreads();
  if (c[t]) base[t] = atomicAdd(&bktcursor[t], c[t]);
  __syncthreads();
#pragma unroll
  for (int i = 0; i < ECH / 256; ++i) {
    int e = e0 + t + i * 256;
    if (e < N_EDGES) {
      int d = ei[N_EDGES + e];
      int b = d >> 8;
      int r = atomicAdd(&c2[b], 1);
      bktbuf[base[b] + r] = (ei[e] << 8) | (d & 255);
    }
  }
}

// B: one block per bucket -> local hist over dst&255, scan, indptr + csr_src.
// All writes land in the bucket's contiguous region (L2-resident window).
__global__ __launch_bounds__(256) void bucket_csr_kernel(const int* __restrict__ bktcount,
                                                         const int* __restrict__ bktbase,
                                                         const int* __restrict__ bktbuf,
                                                         int* __restrict__ indptr,
                                                         int* __restrict__ csr_src) {
  __shared__ int cnt[256], loff[256], sm[256], cnt2[256];
  const int t = threadIdx.x;
  const int b = blockIdx.x;
  const int nb = bktcount[b];
  const int b0 = bktbase[b];
  cnt[t] = 0; cnt2[t] = 0;
  __syncthreads();
  for (int i = t; i < nb; i += 256) atomicAdd(&cnt[bktbuf[b0 + i] & 255], 1);
  __syncthreads();
  int v = cnt[t];
  sm[t] = v;
  __syncthreads();
  for (int off = 1; off < 256; off <<= 1) {
    int add = (t >= off) ? sm[t - off] : 0;
    __syncthreads();
    sm[t] += add;
    __syncthreads();
  }
  loff[t] = sm[t] - v;                 // exclusive within bucket
  int node = b * 256 + t;
  if (node < N_NODES) indptr[node] = b0 + sm[t] - v;
  __syncthreads();
  for (int i = t; i < nb; i += 256) {
    int p = bktbuf[b0 + i];
    int d = p & 255;
    int r = atomicAdd(&cnt2[d], 1);
    csr_src[b0 + loff[d] + r] = p >> 8;
  }
}

// ---------------------------------------------------------------------------
// Layer-1 aggregation v2 (unchanged, validated).
// ---------------------------------------------------------------------------
__global__ __launch_bounds__(256) void agg1_kernel(
    const int* __restrict__ indptr, const int* __restrict__ csr_src,
    const float* __restrict__ h1, const float* __restrict__ a_s,
    const float* __restrict__ a_d, const float* __restrict__ b1,
    float* __restrict__ outbuf) {
  __shared__ float wls[4][HEADS][68];
  __shared__ int   sls[4][64];
  const int wave = threadIdx.x >> 6;
  const int lane = threadIdx.x & 63;
  const int node = blockIdx.x * 4 + wave;
  if (node >= N_NODES) return;
  const int head = lane >> 3;
  const int ch = lane * 2;
  float ad8[8];
#pragma unroll
  for (int h = 0; h < HEADS; ++h) ad8[h] = a_d[node * HEADS + h];
  const float ad_own = ad8[head];
  float e0 = a_s[node * HEADS + head] + ad_own;
  e0 = (e0 >= 0.f) ? e0 : NEG_SLOPE * e0;
  float w0 = __expf(e0);
  float2 hv = *(const float2*)&h1[node * C1 + ch];
  float ax0 = w0 * hv.x, ax1 = 0.f, ax2 = 0.f, ax3 = 0.f;
  float ay0 = w0 * hv.y, ay1 = 0.f, ay2 = 0.f, ay3 = 0.f;
  float dd0 = w0, dd1 = 0.f, dd2 = 0.f, dd3 = 0.f;
  const int start = indptr[node], end = indptr[node + 1];
  for (int j = start; j < end; j += 64) {
    const int cnt = min(64, end - j);
    if (lane < cnt) {
      int s = csr_src[j + lane];
      sls[wave][lane] = s;
      const float* asp = a_s + s * HEADS;
      float4 A = *(const float4*)asp;
      float4 B = *(const float4*)(asp + 4);
      float e;
      e = A.x + ad8[0]; e = (e >= 0.f) ? e : NEG_SLOPE * e; wls[wave][0][lane] = __expf(e);
      e = A.y + ad8[1]; e = (e >= 0.f) ? e : NEG_SLOPE * e; wls[wave][1][lane] = __expf(e);
      e = A.z + ad8[2]; e = (e >= 0.f) ? e : NEG_SLOPE * e; wls[wave][2][lane] = __expf(e);
      e = A.w + ad8[3]; e = (e >= 0.f) ? e : NEG_SLOPE * e; wls[wave][3][lane] = __expf(e);
      e = B.x + ad8[4]; e = (e >= 0.f) ? e : NEG_SLOPE * e; wls[wave][4][lane] = __expf(e);
      e = B.y + ad8[5]; e = (e >= 0.f) ? e : NEG_SLOPE * e; wls[wave][5][lane] = __expf(e);
      e = B.z + ad8[6]; e = (e >= 0.f) ? e : NEG_SLOPE * e; wls[wave][6][lane] = __expf(e);
      e = B.w + ad8[7]; e = (e >= 0.f) ? e : NEG_SLOPE * e; wls[wave][7][lane] = __expf(e);
    }
    asm volatile("s_waitcnt lgkmcnt(0)" ::: "memory");
    int i = 0;
    for (; i + 4 <= cnt; i += 4) {
      int4 sv = *(const int4*)&sls[wave][i];
      float4 wv = *(const float4*)&wls[wave][head][i];
      float2 g0 = *(const float2*)&h1[sv.x * C1 + ch];
      float2 g1 = *(const float2*)&h1[sv.y * C1 + ch];
      float2 g2 = *(const float2*)&h1[sv.z * C1 + ch];
      float2 g3 = *(const float2*)&h1[sv.w * C1 + ch];
      ax0 = fmaf(wv.x, g0.x, ax0); ay0 = fmaf(wv.x, g0.y, ay0); dd0 += wv.x;
      ax1 = fmaf(wv.y, g1.x, ax1); ay1 = fmaf(wv.y, g1.y, ay1); dd1 += wv.y;
      ax2 = fmaf(wv.z, g2.x, ax2); ay2 = fmaf(wv.z, g2.y, ay2); dd2 += wv.z;
      ax3 = fmaf(wv.w, g3.x, ax3); ay3 = fmaf(wv.w, g3.y, ay3); dd3 += wv.w;
    }
    for (; i < cnt; ++i) {
      int s = sls[wave][i];
      float w = wls[wave][head][i];
      float2 g = *(const float2*)&h1[s * C1 + ch];
      ax0 = fmaf(w, g.x, ax0); ay0 = fmaf(w, g.y, ay0); dd0 += w;
    }
  }
  float inv = 1.0f / (dd0 + dd1 + dd2 + dd3 + EPS_GAT);
  float2 bv = *(const float2*)&b1[ch];
  float ox = (ax0 + ax1 + ax2 + ax3) * inv + bv.x;
  float oy = (ay0 + ay1 + ay2 + ay3) * inv + bv.y;
  *(float2*)&outbuf[node * C1 + ch] = make_float2(ox, oy);
}

// ---------------------------------------------------------------------------
// GEMM2 (unchanged, validated).
// ---------------------------------------------------------------------------
__global__ __launch_bounds__(256) void gemm2_kernel(
    const float* __restrict__ conv1out, const float* __restrict__ W2,
    const float* __restrict__ att_s, const float* __restrict__ att_d,
    float* __restrict__ h2, float* __restrict__ a_s2, float* __restrict__ a_d2) {
  __shared__ float w2s[C1 * CLS];
  __shared__ float xs_t[32][132];
  const int t = threadIdx.x;
  const int r0 = blockIdx.x * 128;
  {
    const float4* wv = (const float4*)W2;
    float4* ws4 = (float4*)w2s;
#pragma unroll
    for (int i = 0; i < 5; ++i) {
      int f4 = t + i * 256;
      ws4[f4] = wv[f4];
    }
  }
  const int tx = t & 7;
  const int ty = t >> 3;
  float acc[4][5] = {};
  for (int k0 = 0; k0 < C1; k0 += 32) {
    __syncthreads();
#pragma unroll
    for (int i = 0; i < 4; ++i) {
      int f4 = t + i * 256;
      int row = f4 >> 3;
      int k4 = (f4 & 7) * 4;
      int grow = min(r0 + row, N_NODES - 1);
      float4 v = *(const float4*)&conv1out[grow * C1 + k0 + k4];
      v.x = (v.x > 0.f) ? v.x : (__expf(v.x) - 1.0f);
      v.y = (v.y > 0.f) ? v.y : (__expf(v.y) - 1.0f);
      v.z = (v.z > 0.f) ? v.z : (__expf(v.z) - 1.0f);
      v.w = (v.w > 0.f) ? v.w : (__expf(v.w) - 1.0f);
      xs_t[k4][row] = v.x; xs_t[k4 + 1][row] = v.y;
      xs_t[k4 + 2][row] = v.z; xs_t[k4 + 3][row] = v.w;
    }
    __syncthreads();
#pragma unroll
    for (int kk = 0; kk < 32; ++kk) {
      float4 av = *(float4*)&xs_t[kk][ty * 4];
      float a[4] = {av.x, av.y, av.z, av.w};
      float b[5];
      const float* wrow = &w2s[(k0 + kk) * CLS + tx];
#pragma unroll
      for (int j = 0; j < 5; ++j) b[j] = wrow[8 * j];
#pragma unroll
      for (int i = 0; i < 4; ++i)
#pragma unroll
        for (int j = 0; j < 5; ++j) acc[i][j] = fmaf(a[i], b[j], acc[i][j]);
    }
  }
  float asc[5], adc[5];
#pragma unroll
  for (int j = 0; j < 5; ++j) { asc[j] = att_s[tx + 8 * j]; adc[j] = att_d[tx + 8 * j]; }
#pragma unroll
  for (int i = 0; i < 4; ++i) {
    int row = r0 + ty * 4 + i;
    float ps = 0.f, pd = 0.f;
#pragma unroll
    for (int j = 0; j < 5; ++j) {
      ps += acc[i][j] * asc[j];
      pd += acc[i][j] * adc[j];
    }
    ps += __shfl_xor(ps, 1); ps += __shfl_xor(ps, 2); ps += __shfl_xor(ps, 4);
    pd += __shfl_xor(pd, 1); pd += __shfl_xor(pd, 2); pd += __shfl_xor(pd, 4);
    if (row < N_NODES) {
#pragma unroll
      for (int j = 0; j < 5; ++j) h2[row * CLS + tx + 8 * j] = acc[i][j];
      if (tx == 0) { a_s2[row] = ps; a_d2[row] = pd; }
    }
  }
}

// ---------------------------------------------------------------------------
// Layer-2 aggregation v2 + log_softmax (unchanged, validated).
// ---------------------------------------------------------------------------
__global__ __launch_bounds__(256) void agg2_kernel(
    const int* __restrict__ indptr, const int* __restrict__ csr_src,
    const float* __restrict__ h2, const float* __restrict__ a_s,
    const float* __restrict__ a_d, const float* __restrict__ b2,
    float* __restrict__ out) {
  __shared__ float wls[4][64];
  __shared__ int   sls[4][64];
  const int wave = threadIdx.x >> 6;
  const int lane = threadIdx.x & 63;
  const int node = blockIdx.x * 4 + wave;
  if (node >= N_NODES) return;
  const bool act = lane < CLS;
  const float ad = a_d[node];
  float e0 = a_s[node] + ad;
  e0 = (e0 >= 0.f) ? e0 : NEG_SLOPE * e0;
  float w0 = __expf(e0);
  float a0 = act ? w0 * h2[node * CLS + lane] : 0.f;
  float a1 = 0.f, a2 = 0.f, a3 = 0.f;
  float dd0 = w0, dd1 = 0.f, dd2 = 0.f, dd3 = 0.f;
  const int start = indptr[node], end = indptr[node + 1];
  for (int j = start; j < end; j += 64) {
    const int cnt = min(64, end - j);
    if (lane < cnt) {
      int s = csr_src[j + lane];
      sls[wave][lane] = s;
      float e = a_s[s] + ad;
      e = (e >= 0.f) ? e : NEG_SLOPE * e;
      wls[wave][lane] = __expf(e);
    }
    asm volatile("s_waitcnt lgkmcnt(0)" ::: "memory");
    int i = 0;
    for (; i + 4 <= cnt; i += 4) {
      int4 sv = *(const int4*)&sls[wave][i];
      float4 wv = *(const float4*)&wls[wave][i];
      float g0 = act ? h2[sv.x * CLS + lane] : 0.f;
      float g1 = act ? h2[sv.y * CLS + lane] : 0.f;
      float g2 = act ? h2[sv.z * CLS + lane] : 0.f;
      float g3 = act ? h2[sv.w * CLS + lane] : 0.f;
      a0 = fmaf(wv.x, g0, a0); dd0 += wv.x;
      a1 = fmaf(wv.y, g1, a1); dd1 += wv.y;
      a2 = fmaf(wv.z, g2, a2); dd2 += wv.z;
      a3 = fmaf(wv.w, g3, a3); dd3 += wv.w;
    }
    for (; i < cnt; ++i) {
      int s = sls[wave][i];
      float w = wls[wave][i];
      float g = act ? h2[s * CLS + lane] : 0.f;
      a0 = fmaf(w, g, a0); dd0 += w;
    }
  }
  float x2 = (a0 + a1 + a2 + a3) / (dd0 + dd1 + dd2 + dd3 + EPS_GAT) + (act ? b2[lane] : 0.f);
  float xm = act ? x2 : -__builtin_inff();
  for (int off = 32; off; off >>= 1) xm = fmaxf(xm, __shfl_xor(xm, off));
  float p = act ? __expf(x2 - xm) : 0.f;
  float ps = p;
  for (int off = 32; off; off >>= 1) ps += __shfl_xor(ps, off);
  float ls = x2 - xm - __logf(ps);
  if (act) out[node * CLS + lane] = ls;
}

// ---------------------------------------------------------------------------
extern "C" void kernel_launch(void* const* d_in, const int* in_sizes, int n_in,
                              void* d_out, int out_size, void* d_ws, size_t ws_size,
                              hipStream_t stream) {
  const float* x        = (const float*)d_in[0];
  const int*   ei       = (const int*)d_in[1];
  const float* W1       = (const float*)d_in[3];
  const float* att_src1 = (const float*)d_in[4];
  const float* att_dst1 = (const float*)d_in[5];
  const float* b1       = (const float*)d_in[6];
  const float* W2       = (const float*)d_in[7];
  const float* att_src2 = (const float*)d_in[8];
  const float* att_dst2 = (const float*)d_in[9];
  const float* b2       = (const float*)d_in[10];

  float* outf    = (float*)d_out;                  // [N*40] log_softmax
  float* outconv = outf + (size_t)N_NODES * CLS;   // [N*128] conv1 output (pre-ELU)

  // workspace layout (4-byte units), ~45 MB total
  float* wsf = (float*)d_ws;
  size_t o = 0;
  float* h1      = wsf + o; o += (size_t)N_NODES * C1;    // 6.4M
  float* a_s1    = wsf + o; o += (size_t)N_NODES * HEADS;
  float* a_d1    = wsf + o; o += (size_t)N_NODES * HEADS;
  float* h2      = wsf + o; o += (size_t)N_NODES * CLS;   // 2M
  float* a_s2    = wsf + o; o += N_NODES;
  float* a_d2    = wsf + o; o += N_NODES;
  int* indptr    = (int*)(wsf + o); o += N_NODES + 4;
  int* bktcount  = (int*)(wsf + o); o += 256;
  int* bktbase   = (int*)(wsf + o); o += 256;
  int* bktcursor = (int*)(wsf + o); o += 256;
  int* bktbuf    = (int*)(wsf + o); o += N_EDGES;
  int* csr_src   = (int*)(wsf + o); o += N_EDGES;
  (void)ws_size;

  gemm1_kernel<<<(N_NODES + 63) / 64, 256, 0, stream>>>(x, W1, att_src1, att_dst1,
                                                        h1, a_s1, a_d1);
  zero256_kernel<<<1, 256, 0, stream>>>(bktcount);
  bucket_count_kernel<<<NBLK_A, 256, 0, stream>>>(ei, bktcount);
  bucket_scan_kernel<<<1, 256, 0, stream>>>(bktcount, bktbase, bktcursor, indptr);
  bucket_scatter_kernel<<<NBLK_A, 256, 0, stream>>>(ei, bktcursor, bktbuf);
  bucket_csr_kernel<<<NBKT, 256, 0, stream>>>(bktcount, bktbase, bktbuf, indptr, csr_src);
  agg1_kernel<<<(N_NODES + 3) / 4, 256, 0, stream>>>(indptr, csr_src, h1, a_s1, a_d1,
                                                     b1, outconv);
  gemm2_kernel<<<(N_NODES + 127) / 128, 256, 0, stream>>>(outconv, W2, att_src2, att_dst2,
                                                          h2, a_s2, a_d2);
  agg2_kernel<<<(N_NODES + 3) / 4, 256, 0, stream>>>(indptr, csr_src, h2, a_s2, a_d2,
                                                     b2, outf);
}

// Round 11
// 309.150 us; speedup vs baseline: 1.6604x; 1.1233x over previous
//
#include <hip/hip_runtime.h>
#include <hip/hip_bf16.h>

#define N_NODES 50000
#define N_EDGES 1000000
#define F_IN 256
#define C1 128      // HEADS*HID
#define HEADS 8
#define CLS 40
#define NEG_SLOPE 0.2f
#define EPS_GAT 1e-16f
#define NBKT 196        // buckets of 256 nodes: dst>>8
#define ECH 4096        // edges per block in bucket passes
#define NBLK_A 245      // ceil(E/ECH)

// round-to-nearest-even f32 -> bf16
static __device__ __forceinline__ unsigned short f2bf(float f) {
  unsigned int u = __float_as_uint(f);
  return (unsigned short)((u + 0x7fffu + ((u >> 16) & 1u)) >> 16);
}

// ---------------------------------------------------------------------------
// GEMM1: h1 = x @ W1  [N,256]x[256,128], fused attention dots.
// Epilogue stores h1 in BF16 (halves agg1's gather bytes + h1 write traffic).
// ---------------------------------------------------------------------------
__global__ __launch_bounds__(256) void gemm1_kernel(
    const float* __restrict__ x, const float* __restrict__ W1,
    const float* __restrict__ att_s, const float* __restrict__ att_d,
    unsigned short* __restrict__ h1b, float* __restrict__ a_s1, float* __restrict__ a_d1) {
  __shared__ float xs_t[32][72];   // [k][row64], pad 72
  __shared__ float ws[32][128];    // [k][col]
  const int t = threadIdx.x;
  const int tx = t & 31, ty = t >> 5;
  const int r0 = blockIdx.x * 64;
  float acc[8][4] = {};
  for (int k0 = 0; k0 < F_IN; k0 += 32) {
    __syncthreads();
    const float4* Wv = (const float4*)(W1 + k0 * C1);
#pragma unroll
    for (int i = 0; i < 4; ++i) {
      int f4 = t + i * 256;
      *(float4*)&ws[f4 >> 5][(f4 & 31) * 4] = Wv[f4];
    }
#pragma unroll
    for (int i = 0; i < 2; ++i) {
      int f4 = t + i * 256;
      int rr = f4 >> 3;
      int k4 = (f4 & 7) * 4;
      int grow = min(r0 + rr, N_NODES - 1);
      float4 v = *(const float4*)&x[grow * F_IN + k0 + k4];
      xs_t[k4][rr] = v.x; xs_t[k4 + 1][rr] = v.y;
      xs_t[k4 + 2][rr] = v.z; xs_t[k4 + 3][rr] = v.w;
    }
    __syncthreads();
#pragma unroll
    for (int kk = 0; kk < 32; ++kk) {
      float4 a0v = *(float4*)&xs_t[kk][ty * 8];
      float4 a1v = *(float4*)&xs_t[kk][ty * 8 + 4];
      float4 bv  = *(float4*)&ws[kk][tx * 4];
      float a[8] = {a0v.x, a0v.y, a0v.z, a0v.w, a1v.x, a1v.y, a1v.z, a1v.w};
      float b[4] = {bv.x, bv.y, bv.z, bv.w};
#pragma unroll
      for (int i = 0; i < 8; ++i)
#pragma unroll
        for (int j = 0; j < 4; ++j) acc[i][j] = fmaf(a[i], b[j], acc[i][j]);
    }
  }
  float as_c[4], ad_c[4];
#pragma unroll
  for (int j = 0; j < 4; ++j) { as_c[j] = att_s[tx * 4 + j]; ad_c[j] = att_d[tx * 4 + j]; }
  const int head = tx >> 2;
#pragma unroll
  for (int i = 0; i < 8; ++i) {
    int row = r0 + ty * 8 + i;
    float ps = acc[i][0] * as_c[0] + acc[i][1] * as_c[1] + acc[i][2] * as_c[2] + acc[i][3] * as_c[3];
    float pd = acc[i][0] * ad_c[0] + acc[i][1] * ad_c[1] + acc[i][2] * ad_c[2] + acc[i][3] * ad_c[3];
    ps += __shfl_xor(ps, 1); ps += __shfl_xor(ps, 2);
    pd += __shfl_xor(pd, 1); pd += __shfl_xor(pd, 2);
    if (row < N_NODES) {
      ushort4 pk;
      pk.x = f2bf(acc[i][0]); pk.y = f2bf(acc[i][1]);
      pk.z = f2bf(acc[i][2]); pk.w = f2bf(acc[i][3]);
      *(ushort4*)&h1b[row * C1 + tx * 4] = pk;
      if ((tx & 3) == 0) { a_s1[row * HEADS + head] = ps; a_d1[row * HEADS + head] = pd; }
    }
  }
}

// ---------------------------------------------------------------------------
// CSR build v3: bucketed (unchanged, validated).
// ---------------------------------------------------------------------------
__global__ void zero256_kernel(int* __restrict__ bktcount) {
  bktcount[threadIdx.x] = 0;
}

__global__ __launch_bounds__(256) void bucket_count_kernel(const int* __restrict__ ei,
                                                           int* __restrict__ bktcount) {
  __shared__ int c[256];
  const int t = threadIdx.x;
  c[t] = 0;
  __syncthreads();
  const int e0 = blockIdx.x * ECH;
#pragma unroll
  for (int i = 0; i < ECH / 256; ++i) {
    int e = e0 + t + i * 256;
    if (e < N_EDGES) atomicAdd(&c[ei[N_EDGES + e] >> 8], 1);
  }
  __syncthreads();
  if (c[t]) atomicAdd(&bktcount[t], c[t]);
}

__global__ __launch_bounds__(256) void bucket_scan_kernel(const int* __restrict__ bktcount,
                                                          int* __restrict__ bktbase,
                                                          int* __restrict__ bktcursor,
                                                          int* __restrict__ indptr) {
  __shared__ int sm[256];
  const int t = threadIdx.x;
  int v = (t < NBKT) ? bktcount[t] : 0;
  sm[t] = v;
  __syncthreads();
  for (int off = 1; off < 256; off <<= 1) {
    int add = (t >= off) ? sm[t - off] : 0;
    __syncthreads();
    sm[t] += add;
    __syncthreads();
  }
  int excl = sm[t] - v;
  bktbase[t] = excl;
  bktcursor[t] = excl;
  if (t == 0) indptr[N_NODES] = N_EDGES;
}

__global__ __launch_bounds__(256) void bucket_scatter_kernel(const int* __restrict__ ei,
                                                             int* __restrict__ bktcursor,
                                                             int* __restrict__ bktbuf) {
  __shared__ int c[256], c2[256], base[256];
  const int t = threadIdx.x;
  c[t] = 0; c2[t] = 0;
  __syncthreads();
  const int e0 = blockIdx.x * ECH;
#pragma unroll
  for (int i = 0; i < ECH / 256; ++i) {
    int e = e0 + t + i * 256;
    if (e < N_EDGES) atomicAdd(&c[ei[N_EDGES + e] >> 8], 1);
  }
  __syncthreads();
  if (c[t]) base[t] = atomicAdd(&bktcursor[t], c[t]);
  __syncthreads();
#pragma unroll
  for (int i = 0; i < ECH / 256; ++i) {
    int e = e0 + t + i * 256;
    if (e < N_EDGES) {
      int d = ei[N_EDGES + e];
      int b = d >> 8;
      int r = atomicAdd(&c2[b], 1);
      bktbuf[base[b] + r] = (ei[e] << 8) | (d & 255);
    }
  }
}

__global__ __launch_bounds__(256) void bucket_csr_kernel(const int* __restrict__ bktcount,
                                                         const int* __restrict__ bktbase,
                                                         const int* __restrict__ bktbuf,
                                                         int* __restrict__ indptr,
                                                         int* __restrict__ csr_src) {
  __shared__ int cnt[256], loff[256], sm[256], cnt2[256];
  const int t = threadIdx.x;
  const int b = blockIdx.x;
  const int nb = bktcount[b];
  const int b0 = bktbase[b];
  cnt[t] = 0; cnt2[t] = 0;
  __syncthreads();
  for (int i = t; i < nb; i += 256) atomicAdd(&cnt[bktbuf[b0 + i] & 255], 1);
  __syncthreads();
  int v = cnt[t];
  sm[t] = v;
  __syncthreads();
  for (int off = 1; off < 256; off <<= 1) {
    int add = (t >= off) ? sm[t - off] : 0;
    __syncthreads();
    sm[t] += add;
    __syncthreads();
  }
  loff[t] = sm[t] - v;
  int node = b * 256 + t;
  if (node < N_NODES) indptr[node] = b0 + sm[t] - v;
  __syncthreads();
  for (int i = t; i < nb; i += 256) {
    int p = bktbuf[b0 + i];
    int d = p & 255;
    int r = atomicAdd(&cnt2[d], 1);
    csr_src[b0 + loff[d] + r] = p >> 8;
  }
}

// ---------------------------------------------------------------------------
// Layer-1 aggregation v3: two-phase as before, but h1 gathered as BF16.
// A wave reads a row as 64 x 4B uints (2 bf16 each): half the bytes of fp32.
// Accumulation stays fp32.
// ---------------------------------------------------------------------------
__global__ __launch_bounds__(256) void agg1_kernel(
    const int* __restrict__ indptr, const int* __restrict__ csr_src,
    const unsigned int* __restrict__ h1u, const float* __restrict__ a_s,
    const float* __restrict__ a_d, const float* __restrict__ b1,
    float* __restrict__ outbuf) {
  __shared__ float wls[4][HEADS][68];
  __shared__ int   sls[4][64];
  const int wave = threadIdx.x >> 6;
  const int lane = threadIdx.x & 63;
  const int node = blockIdx.x * 4 + wave;
  if (node >= N_NODES) return;
  const int head = lane >> 3;
  const int ch = lane * 2;
  float ad8[8];
#pragma unroll
  for (int h = 0; h < HEADS; ++h) ad8[h] = a_d[node * HEADS + h];
  const float ad_own = ad8[head];
  float e0 = a_s[node * HEADS + head] + ad_own;
  e0 = (e0 >= 0.f) ? e0 : NEG_SLOPE * e0;
  float w0 = __expf(e0);
  unsigned int sv0 = h1u[node * 64 + lane];
  float ax0 = w0 * __uint_as_float(sv0 << 16);
  float ay0 = w0 * __uint_as_float(sv0 & 0xffff0000u);
  float ax1 = 0.f, ax2 = 0.f, ax3 = 0.f;
  float ay1 = 0.f, ay2 = 0.f, ay3 = 0.f;
  float dd0 = w0, dd1 = 0.f, dd2 = 0.f, dd3 = 0.f;
  const int start = indptr[node], end = indptr[node + 1];
  for (int j = start; j < end; j += 64) {
    const int cnt = min(64, end - j);
    if (lane < cnt) {
      int s = csr_src[j + lane];
      sls[wave][lane] = s;
      const float* asp = a_s + s * HEADS;
      float4 A = *(const float4*)asp;
      float4 B = *(const float4*)(asp + 4);
      float e;
      e = A.x + ad8[0]; e = (e >= 0.f) ? e : NEG_SLOPE * e; wls[wave][0][lane] = __expf(e);
      e = A.y + ad8[1]; e = (e >= 0.f) ? e : NEG_SLOPE * e; wls[wave][1][lane] = __expf(e);
      e = A.z + ad8[2]; e = (e >= 0.f) ? e : NEG_SLOPE * e; wls[wave][2][lane] = __expf(e);
      e = A.w + ad8[3]; e = (e >= 0.f) ? e : NEG_SLOPE * e; wls[wave][3][lane] = __expf(e);
      e = B.x + ad8[4]; e = (e >= 0.f) ? e : NEG_SLOPE * e; wls[wave][4][lane] = __expf(e);
      e = B.y + ad8[5]; e = (e >= 0.f) ? e : NEG_SLOPE * e; wls[wave][5][lane] = __expf(e);
      e = B.z + ad8[6]; e = (e >= 0.f) ? e : NEG_SLOPE * e; wls[wave][6][lane] = __expf(e);
      e = B.w + ad8[7]; e = (e >= 0.f) ? e : NEG_SLOPE * e; wls[wave][7][lane] = __expf(e);
    }
    asm volatile("s_waitcnt lgkmcnt(0)" ::: "memory");
    int i = 0;
    for (; i + 4 <= cnt; i += 4) {
      int4 sv = *(const int4*)&sls[wave][i];
      float4 wv = *(const float4*)&wls[wave][head][i];
      unsigned int g0 = h1u[sv.x * 64 + lane];
      unsigned int g1 = h1u[sv.y * 64 + lane];
      unsigned int g2 = h1u[sv.z * 64 + lane];
      unsigned int g3 = h1u[sv.w * 64 + lane];
      ax0 = fmaf(wv.x, __uint_as_float(g0 << 16), ax0);
      ay0 = fmaf(wv.x, __uint_as_float(g0 & 0xffff0000u), ay0); dd0 += wv.x;
      ax1 = fmaf(wv.y, __uint_as_float(g1 << 16), ax1);
      ay1 = fmaf(wv.y, __uint_as_float(g1 & 0xffff0000u), ay1); dd1 += wv.y;
      ax2 = fmaf(wv.z, __uint_as_float(g2 << 16), ax2);
      ay2 = fmaf(wv.z, __uint_as_float(g2 & 0xffff0000u), ay2); dd2 += wv.z;
      ax3 = fmaf(wv.w, __uint_as_float(g3 << 16), ax3);
      ay3 = fmaf(wv.w, __uint_as_float(g3 & 0xffff0000u), ay3); dd3 += wv.w;
    }
    for (; i < cnt; ++i) {
      int s = sls[wave][i];
      float w = wls[wave][head][i];
      unsigned int g = h1u[s * 64 + lane];
      ax0 = fmaf(w, __uint_as_float(g << 16), ax0);
      ay0 = fmaf(w, __uint_as_float(g & 0xffff0000u), ay0); dd0 += w;
    }
  }
  float inv = 1.0f / (dd0 + dd1 + dd2 + dd3 + EPS_GAT);
  float2 bv = *(const float2*)&b1[ch];
  float ox = (ax0 + ax1 + ax2 + ax3) * inv + bv.x;
  float oy = (ay0 + ay1 + ay2 + ay3) * inv + bv.y;
  *(float2*)&outbuf[node * C1 + ch] = make_float2(ox, oy);
}

// ---------------------------------------------------------------------------
// GEMM2 (unchanged, validated).
// ---------------------------------------------------------------------------
__global__ __launch_bounds__(256) void gemm2_kernel(
    const float* __restrict__ conv1out, const float* __restrict__ W2,
    const float* __restrict__ att_s, const float* __restrict__ att_d,
    float* __restrict__ h2, float* __restrict__ a_s2, float* __restrict__ a_d2) {
  __shared__ float w2s[C1 * CLS];
  __shared__ float xs_t[32][132];
  const int t = threadIdx.x;
  const int r0 = blockIdx.x * 128;
  {
    const float4* wv = (const float4*)W2;
    float4* ws4 = (float4*)w2s;
#pragma unroll
    for (int i = 0; i < 5; ++i) {
      int f4 = t + i * 256;
      ws4[f4] = wv[f4];
    }
  }
  const int tx = t & 7;
  const int ty = t >> 3;
  float acc[4][5] = {};
  for (int k0 = 0; k0 < C1; k0 += 32) {
    __syncthreads();
#pragma unroll
    for (int i = 0; i < 4; ++i) {
      int f4 = t + i * 256;
      int row = f4 >> 3;
      int k4 = (f4 & 7) * 4;
      int grow = min(r0 + row, N_NODES - 1);
      float4 v = *(const float4*)&conv1out[grow * C1 + k0 + k4];
      v.x = (v.x > 0.f) ? v.x : (__expf(v.x) - 1.0f);
      v.y = (v.y > 0.f) ? v.y : (__expf(v.y) - 1.0f);
      v.z = (v.z > 0.f) ? v.z : (__expf(v.z) - 1.0f);
      v.w = (v.w > 0.f) ? v.w : (__expf(v.w) - 1.0f);
      xs_t[k4][row] = v.x; xs_t[k4 + 1][row] = v.y;
      xs_t[k4 + 2][row] = v.z; xs_t[k4 + 3][row] = v.w;
    }
    __syncthreads();
#pragma unroll
    for (int kk = 0; kk < 32; ++kk) {
      float4 av = *(float4*)&xs_t[kk][ty * 4];
      float a[4] = {av.x, av.y, av.z, av.w};
      float b[5];
      const float* wrow = &w2s[(k0 + kk) * CLS + tx];
#pragma unroll
      for (int j = 0; j < 5; ++j) b[j] = wrow[8 * j];
#pragma unroll
      for (int i = 0; i < 4; ++i)
#pragma unroll
        for (int j = 0; j < 5; ++j) acc[i][j] = fmaf(a[i], b[j], acc[i][j]);
    }
  }
  float asc[5], adc[5];
#pragma unroll
  for (int j = 0; j < 5; ++j) { asc[j] = att_s[tx + 8 * j]; adc[j] = att_d[tx + 8 * j]; }
#pragma unroll
  for (int i = 0; i < 4; ++i) {
    int row = r0 + ty * 4 + i;
    float ps = 0.f, pd = 0.f;
#pragma unroll
    for (int j = 0; j < 5; ++j) {
      ps += acc[i][j] * asc[j];
      pd += acc[i][j] * adc[j];
    }
    ps += __shfl_xor(ps, 1); ps += __shfl_xor(ps, 2); ps += __shfl_xor(ps, 4);
    pd += __shfl_xor(pd, 1); pd += __shfl_xor(pd, 2); pd += __shfl_xor(pd, 4);
    if (row < N_NODES) {
#pragma unroll
      for (int j = 0; j < 5; ++j) h2[row * CLS + tx + 8 * j] = acc[i][j];
      if (tx == 0) { a_s2[row] = ps; a_d2[row] = pd; }
    }
  }
}

// ---------------------------------------------------------------------------
// Layer-2 aggregation v2 + log_softmax (unchanged, validated).
// ---------------------------------------------------------------------------
__global__ __launch_bounds__(256) void agg2_kernel(
    const int* __restrict__ indptr, const int* __restrict__ csr_src,
    const float* __restrict__ h2, const float* __restrict__ a_s,
    const float* __restrict__ a_d, const float* __restrict__ b2,
    float* __restrict__ out) {
  __shared__ float wls[4][64];
  __shared__ int   sls[4][64];
  const int wave = threadIdx.x >> 6;
  const int lane = threadIdx.x & 63;
  const int node = blockIdx.x * 4 + wave;
  if (node >= N_NODES) return;
  const bool act = lane < CLS;
  const float ad = a_d[node];
  float e0 = a_s[node] + ad;
  e0 = (e0 >= 0.f) ? e0 : NEG_SLOPE * e0;
  float w0 = __expf(e0);
  float a0 = act ? w0 * h2[node * CLS + lane] : 0.f;
  float a1 = 0.f, a2 = 0.f, a3 = 0.f;
  float dd0 = w0, dd1 = 0.f, dd2 = 0.f, dd3 = 0.f;
  const int start = indptr[node], end = indptr[node + 1];
  for (int j = start; j < end; j += 64) {
    const int cnt = min(64, end - j);
    if (lane < cnt) {
      int s = csr_src[j + lane];
      sls[wave][lane] = s;
      float e = a_s[s] + ad;
      e = (e >= 0.f) ? e : NEG_SLOPE * e;
      wls[wave][lane] = __expf(e);
    }
    asm volatile("s_waitcnt lgkmcnt(0)" ::: "memory");
    int i = 0;
    for (; i + 4 <= cnt; i += 4) {
      int4 sv = *(const int4*)&sls[wave][i];
      float4 wv = *(const float4*)&wls[wave][i];
      float g0 = act ? h2[sv.x * CLS + lane] : 0.f;
      float g1 = act ? h2[sv.y * CLS + lane] : 0.f;
      float g2 = act ? h2[sv.z * CLS + lane] : 0.f;
      float g3 = act ? h2[sv.w * CLS + lane] : 0.f;
      a0 = fmaf(wv.x, g0, a0); dd0 += wv.x;
      a1 = fmaf(wv.y, g1, a1); dd1 += wv.y;
      a2 = fmaf(wv.z, g2, a2); dd2 += wv.z;
      a3 = fmaf(wv.w, g3, a3); dd3 += wv.w;
    }
    for (; i < cnt; ++i) {
      int s = sls[wave][i];
      float w = wls[wave][i];
      float g = act ? h2[s * CLS + lane] : 0.f;
      a0 = fmaf(w, g, a0); dd0 += w;
    }
  }
  float x2 = (a0 + a1 + a2 + a3) / (dd0 + dd1 + dd2 + dd3 + EPS_GAT) + (act ? b2[lane] : 0.f);
  float xm = act ? x2 : -__builtin_inff();
  for (int off = 32; off; off >>= 1) xm = fmaxf(xm, __shfl_xor(xm, off));
  float p = act ? __expf(x2 - xm) : 0.f;
  float ps = p;
  for (int off = 32; off; off >>= 1) ps += __shfl_xor(ps, off);
  float ls = x2 - xm - __logf(ps);
  if (act) out[node * CLS + lane] = ls;
}

// ---------------------------------------------------------------------------
extern "C" void kernel_launch(void* const* d_in, const int* in_sizes, int n_in,
                              void* d_out, int out_size, void* d_ws, size_t ws_size,
                              hipStream_t stream) {
  const float* x        = (const float*)d_in[0];
  const int*   ei       = (const int*)d_in[1];
  const float* W1       = (const float*)d_in[3];
  const float* att_src1 = (const float*)d_in[4];
  const float* att_dst1 = (const float*)d_in[5];
  const float* b1       = (const float*)d_in[6];
  const float* W2       = (const float*)d_in[7];
  const float* att_src2 = (const float*)d_in[8];
  const float* att_dst2 = (const float*)d_in[9];
  const float* b2       = (const float*)d_in[10];

  float* outf    = (float*)d_out;                  // [N*40] log_softmax
  float* outconv = outf + (size_t)N_NODES * CLS;   // [N*128] conv1 output (pre-ELU)

  // workspace layout (4-byte units), ~39 MB total
  float* wsf = (float*)d_ws;
  size_t o = 0;
  unsigned short* h1b = (unsigned short*)(wsf + o); o += (size_t)N_NODES * C1 / 2;  // bf16, 12.8MB
  float* a_s1    = wsf + o; o += (size_t)N_NODES * HEADS;
  float* a_d1    = wsf + o; o += (size_t)N_NODES * HEADS;
  float* h2      = wsf + o; o += (size_t)N_NODES * CLS;   // 2M
  float* a_s2    = wsf + o; o += N_NODES;
  float* a_d2    = wsf + o; o += N_NODES;
  int* indptr    = (int*)(wsf + o); o += N_NODES + 4;
  int* bktcount  = (int*)(wsf + o); o += 256;
  int* bktbase   = (int*)(wsf + o); o += 256;
  int* bktcursor = (int*)(wsf + o); o += 256;
  int* bktbuf    = (int*)(wsf + o); o += N_EDGES;
  int* csr_src   = (int*)(wsf + o); o += N_EDGES;
  (void)ws_size;

  gemm1_kernel<<<(N_NODES + 63) / 64, 256, 0, stream>>>(x, W1, att_src1, att_dst1,
                                                        h1b, a_s1, a_d1);
  zero256_kernel<<<1, 256, 0, stream>>>(bktcount);
  bucket_count_kernel<<<NBLK_A, 256, 0, stream>>>(ei, bktcount);
  bucket_scan_kernel<<<1, 256, 0, stream>>>(bktcount, bktbase, bktcursor, indptr);
  bucket_scatter_kernel<<<NBLK_A, 256, 0, stream>>>(ei, bktcursor, bktbuf);
  bucket_csr_kernel<<<NBKT, 256, 0, stream>>>(bktcount, bktbase, bktbuf, indptr, csr_src);
  agg1_kernel<<<(N_NODES + 3) / 4, 256, 0, stream>>>(indptr, csr_src,
                                                     (const unsigned int*)h1b, a_s1, a_d1,
                                                     b1, outconv);
  gemm2_kernel<<<(N_NODES + 127) / 128, 256, 0, stream>>>(outconv, W2, att_src2, att_dst2,
                                                          h2, a_s2, a_d2);
  agg2_kernel<<<(N_NODES + 3) / 4, 256, 0, stream>>>(indptr, csr_src, h2, a_s2, a_d2,
                                                     b2, outf);
}